// Round 8
// baseline (274.280 us; speedup 1.0000x reference)
//
#include <hip/hip_runtime.h>

typedef __attribute__((ext_vector_type(8))) short short8v;
typedef __attribute__((ext_vector_type(4))) float float4v;
typedef unsigned short u16;

constexpr int B_ = 32, T_ = 128, J_ = 24, H_ = 256;
constexpr int BT_ = B_ * T_;   // 4096
constexpr int M_  = BT_ * J_;  // 98304
constexpr float BN_EPS_ = 1e-5f, SLOPE_ = 0.2f;

// ---- workspace byte offsets ----
constexpr size_t OB_HGB  = 0;                              // bf16 [M][256] hg -> h2 (in place)
constexpr size_t OB_HB   = OB_HGB + (size_t)M_ * H_ * 2;   // bf16 [M][256] residual h
constexpr size_t OB_WTF  = OB_HB  + (size_t)M_ * H_ * 2;   // bf16 768*256 frag-packed conv W
constexpr size_t OB_WGF  = OB_WTF + 768 * 256 * 2;         // bf16 256*256 frag-packed gcn W
constexpr size_t OB_BASE = OB_WGF + 256 * 256 * 2;         // f32 [BT][256]
constexpr size_t OB_BNSC = OB_BASE + (size_t)BT_ * H_ * 4; // f32 256
constexpr size_t OB_BNSH = OB_BNSC + 256 * 4;              // f32 256

__device__ __forceinline__ u16 f2b(float f) {
  union { float f; unsigned u; } v; v.f = f;
  return (u16)((v.u + 0x7fffu + ((v.u >> 16) & 1u)) >> 16);
}
__device__ __forceinline__ float b2f(u16 u) {
  union { unsigned u; float f; } v; v.u = ((unsigned)u) << 16; return v.f;
}

// ================================================================ k_pack2 (unchanged)
__global__ __launch_bounds__(256) void k_pack2(
    const float* __restrict__ w_conv, const float* __restrict__ w_gcn,
    const float* __restrict__ gamma, const float* __restrict__ beta,
    const float* __restrict__ mean, const float* __restrict__ var,
    u16* __restrict__ wtf, u16* __restrict__ wgf,
    float* __restrict__ bnsc, float* __restrict__ bnsh) {
  __shared__ float wlds[12288];  // 48 KB
  int bid = blockIdx.x, tid = threadIdx.x;
  if (bid < 16) {
    int nblk = bid, o0 = nblk * 16;
#pragma unroll
    for (int p = 0; p < 12; ++p) {
      int lin = tid + p * 256;
      int row = lin / 192, c4 = lin % 192;
      *(float4*)&wlds[row * 768 + c4 * 4] =
          *(const float4*)&w_conv[(size_t)(o0 + row) * 768 + c4 * 4];
    }
    __syncthreads();
#pragma unroll
    for (int p = 0; p < 6; ++p) {
      int unit = tid + p * 256;
      int kb = unit >> 6, l = unit & 63;
      int col = l & 15, kb8 = (l >> 4) * 8;
      u16 tmp[8];
#pragma unroll
      for (int j = 0; j < 8; ++j) {
        int k = kb * 32 + kb8 + j;
        int tap = k >> 8, i = k & 255;
        tmp[j] = f2b(wlds[col * 768 + i * 3 + tap]);
      }
      *(short8v*)&wtf[((size_t)kb * 16 + nblk) * 512 + l * 8] = *(short8v*)tmp;
    }
  } else if (bid < 24) {
    int kb = bid - 16;
#pragma unroll
    for (int p = 0; p < 8; ++p) {
      int lin = tid + p * 256;
      int row = lin >> 6, c4 = lin & 63;
      *(float4*)&wlds[row * 256 + c4 * 4] =
          *(const float4*)&w_gcn[((size_t)kb * 32 + row) * 256 + c4 * 4];
    }
    __syncthreads();
#pragma unroll
    for (int p = 0; p < 4; ++p) {
      int unit = tid + p * 256;
      int nblk = unit >> 6, l = unit & 63;
      int col = l & 15, kb8 = (l >> 4) * 8;
      u16 tmp[8];
#pragma unroll
      for (int j = 0; j < 8; ++j)
        tmp[j] = f2b(wlds[(kb8 + j) * 256 + nblk * 16 + col]);
      *(short8v*)&wgf[((size_t)kb * 16 + nblk) * 512 + l * 8] = *(short8v*)tmp;
    }
  } else {
    float sc = gamma[tid] * rsqrtf(var[tid] + BN_EPS_);
    bnsc[tid] = sc;
    bnsh[tid] = beta[tid] - mean[tid] * sc;
  }
}

// ================================================================ k_base2 (unchanged)
__global__ __launch_bounds__(256) void k_base2(
    const float* __restrict__ tau, const float* __restrict__ w_t1,
    const float* __restrict__ b_t1, const float* __restrict__ z,
    const float* __restrict__ hn, const float* __restrict__ w_t2,
    const float* __restrict__ w_radar, const float* __restrict__ b_t2,
    const float* __restrict__ b_radar, float* __restrict__ basep) {
  __shared__ float As[16][40];
  __shared__ float Bs[16][128];
  int bm = blockIdx.x & 127, bn = blockIdx.x >> 7;
  int row0 = bm * 32, col0 = bn * 128;
  int tid = threadIdx.x, ty = tid >> 5, tx = tid & 31;
  int sr = tid >> 2, sq = tid & 3;
  float tauv = (tid < 128) ? tau[row0 + sr] : 0.f;
  int bb = bm >> 2;
  float acc[4][4] = {};
  for (int ck = 0; ck < 32; ++ck) {
    int half = ck >> 4;
    int k0 = (ck & 15) * 16;
    if (tid < 128) {
      int kk4 = k0 + sq * 4;
      float4 v;
      if (half == 0) {
        float4 w1  = *(const float4*)&w_t1[kk4];
        float4 bb1 = *(const float4*)&b_t1[kk4];
        float t0 = tauv * w1.x + bb1.x, t1 = tauv * w1.y + bb1.y;
        float t2 = tauv * w1.z + bb1.z, t3 = tauv * w1.w + bb1.w;
        v.x = t0 / (1.f + expf(-t0)); v.y = t1 / (1.f + expf(-t1));
        v.z = t2 / (1.f + expf(-t2)); v.w = t3 / (1.f + expf(-t3));
      } else {
        float4 zv = *(const float4*)&z[(size_t)(row0 + sr) * 256 + kk4];
        float4 hv = *(const float4*)&hn[(size_t)bb * 256 + kk4];
        v = make_float4(zv.x + hv.x, zv.y + hv.y, zv.z + hv.z, zv.w + hv.w);
      }
      As[sq * 4 + 0][sr] = v.x; As[sq * 4 + 1][sr] = v.y;
      As[sq * 4 + 2][sr] = v.z; As[sq * 4 + 3][sr] = v.w;
    }
    const float* W = half ? w_radar : w_t2;
#pragma unroll
    for (int p = 0; p < 2; ++p) {
      int idx = tid + p * 256;
      int br = idx >> 5, c4 = idx & 31;
      *(float4*)&Bs[br][c4 * 4] = *(const float4*)&W[(size_t)(k0 + br) * 256 + col0 + c4 * 4];
    }
    __syncthreads();
#pragma unroll
    for (int kk = 0; kk < 16; ++kk) {
      float4 av = *(const float4*)&As[kk][ty * 4];
      float4 bv = *(const float4*)&Bs[kk][tx * 4];
      float a[4] = {av.x, av.y, av.z, av.w};
      float b[4] = {bv.x, bv.y, bv.z, bv.w};
#pragma unroll
      for (int i = 0; i < 4; ++i)
#pragma unroll
        for (int j = 0; j < 4; ++j) acc[i][j] += a[i] * b[j];
    }
    __syncthreads();
  }
#pragma unroll
  for (int i = 0; i < 4; ++i) {
    int bt = row0 + ty * 4 + i;
    int c = col0 + tx * 4;
    float4 o;
    o.x = acc[i][0] + b_t2[c + 0] + b_radar[c + 0];
    o.y = acc[i][1] + b_t2[c + 1] + b_radar[c + 1];
    o.z = acc[i][2] + b_t2[c + 2] + b_radar[c + 2];
    o.w = acc[i][3] + b_t2[c + 3] + b_radar[c + 3];
    *(float4*)&basep[(size_t)bt * 256 + c] = o;
  }
}

// ================================================================ k_hg2 (unchanged)
__global__ __launch_bounds__(256) void k_hg2(
    const float* __restrict__ xt, const float* __restrict__ basep,
    const float* __restrict__ adj, const float* __restrict__ w_joint,
    const float* __restrict__ b_joint, u16* __restrict__ hgb,
    u16* __restrict__ hb) {
  __shared__ float xs[72];
  __shared__ __align__(16) u16 stage[2][24][256];  // 24 KB
  int bt = blockIdx.x, c = threadIdx.x;
  if (c < 18) ((float4*)xs)[c] = ((const float4*)(xt + (size_t)bt * 72))[c];
  __syncthreads();
  float wj0 = w_joint[c], wj1 = w_joint[256 + c], wj2 = w_joint[512 + c];
  float hbase = b_joint[c] + basep[(size_t)bt * 256 + c];
  float hv[24];
#pragma unroll
  for (int j = 0; j < 24; ++j) {
    hv[j] = xs[3 * j] * wj0 + xs[3 * j + 1] * wj1 + xs[3 * j + 2] * wj2 + hbase;
    stage[0][j][c] = f2b(hv[j]);
  }
  float ag[24] = {};
#pragma unroll
  for (int kp = 0; kp < 24; ++kp) {
    float av = hv[kp];
#pragma unroll
    for (int j = 0; j < 24; ++j) ag[j] += adj[j * 24 + kp] * av;
  }
#pragma unroll
  for (int j = 0; j < 24; ++j) stage[1][j][c] = f2b(ag[j]);
  __syncthreads();
  size_t gro = (size_t)bt * 24 * 256;
#pragma unroll
  for (int p = 0; p < 3; ++p) {
    int uu = c + p * 256;
    int j = uu >> 5, c8 = uu & 31;
    *(short8v*)&hb[gro + j * 256 + c8 * 8] = *(const short8v*)&stage[0][j][c8 * 8];
  }
#pragma unroll
  for (int p = 0; p < 3; ++p) {
    int uu = c + p * 256;
    int j = uu >> 5, c8 = uu & 31;
    *(short8v*)&hgb[gro + j * 256 + c8 * 8] = *(const short8v*)&stage[1][j][c8 * 8];
  }
}

// ================================================================ 128-row MFMA GEMMs, 8 waves (2m x 4n)
#define DO_MFMA(A_, B_) do {                                              \
  _Pragma("unroll") for (int mi_ = 0; mi_ < 4; ++mi_)                     \
  _Pragma("unroll") for (int ni_ = 0; ni_ < 4; ++ni_)                     \
    acc[mi_][ni_] = __builtin_amdgcn_mfma_f32_16x16x32_bf16(              \
        A_[mi_], B_[ni_], acc[mi_][ni_], 0, 0, 0);                        \
} while (0)

__global__ __launch_bounds__(512, 2) void k_gcn4(
    const u16* __restrict__ wgf, const float* __restrict__ b_gcn,
    const u16* __restrict__ hb, u16* __restrict__ hgb) {
  __shared__ u16 Asm[128 * 256];  // 64 KB
  int tid = threadIdx.x;
  int l = tid & 63, w = tid >> 6;        // 8 waves
  int wm = w >> 2, wn = w & 3;           // 2m x 4n
  int l15 = l & 15, hi16 = (l >> 4) * 16, l8 = l * 8;
  int bid = blockIdx.x;
  int swz = (bid & 7) * 96 + (bid >> 3); // 768 = 8*96, bijective
  int r0 = swz * 128;
  char* ab = (char*)Asm;

#pragma unroll
  for (int p = 0; p < 8; ++p) {
    int c = tid + p * 512;
    int lr = c >> 5, c16 = c & 31;
    short8v v = *(const short8v*)&hgb[(size_t)(r0 + lr) * 256 + c16 * 8];
    int off = (lr * 512 + c16 * 16) ^ ((lr & 7) << 4);
    *(short8v*)(ab + off) = v;
  }
  __syncthreads();

  float4v z4 = {0.f, 0.f, 0.f, 0.f};
  float4v acc[4][4];
#pragma unroll
  for (int mi = 0; mi < 4; ++mi)
#pragma unroll
    for (int ni = 0; ni < 4; ++ni) acc[mi][ni] = z4;

  const u16* wbase = wgf + (size_t)wn * 4 * 512 + l8;

#define LB_G(dst, kb) do {                                                \
  const u16* bp_ = wbase + (size_t)(kb) * 16 * 512;                       \
  _Pragma("unroll") for (int ni_ = 0; ni_ < 4; ++ni_)                     \
    dst[ni_] = *(const short8v*)(bp_ + ni_ * 512);                        \
} while (0)
#define LA_G(dst, kb) do {                                                \
  _Pragma("unroll") for (int mi_ = 0; mi_ < 4; ++mi_) {                   \
    int lr_ = wm * 64 + mi_ * 16 + l15;                                   \
    int off_ = (lr_ * 512 + (kb) * 64 + hi16) ^ ((lr_ & 7) << 4);         \
    dst[mi_] = *(const short8v*)(ab + off_);                              \
  }                                                                       \
} while (0)

  short8v a0[4], a1[4], b0[4], b1[4];
  LB_G(b0, 0); LB_G(b1, 1); LA_G(a0, 0); LA_G(a1, 1);
#pragma unroll
  for (int kb2 = 0; kb2 < 8; kb2 += 2) {
    DO_MFMA(a0, b0);
    if (kb2 + 2 < 8) { LB_G(b0, kb2 + 2); LA_G(a0, kb2 + 2); }
    DO_MFMA(a1, b1);
    if (kb2 + 3 < 8) { LB_G(b1, kb2 + 3); LA_G(a1, kb2 + 3); }
  }
#undef LB_G
#undef LA_G

  int g = l >> 4;
#pragma unroll
  for (int ni = 0; ni < 4; ++ni) {
    int col = wn * 64 + ni * 16 + l15;
    float bg = b_gcn[col];
#pragma unroll
    for (int mi = 0; mi < 4; ++mi)
#pragma unroll
      for (int r = 0; r < 4; ++r) {
        int row = r0 + wm * 64 + mi * 16 + g * 4 + r;
        float hres = b2f(hb[(size_t)row * 256 + col]);
        float gv = acc[mi][ni][r] + bg;
        hgb[(size_t)row * 256 + col] = f2b(hres + (gv > 0.f ? gv : 0.f));
      }
  }
}

__global__ __launch_bounds__(512, 2) void k_conv4(
    const u16* __restrict__ wtf, const float* __restrict__ b_conv,
    const float* __restrict__ bnsc, const float* __restrict__ bnsh,
    const float* __restrict__ w_out, const float* __restrict__ b_out,
    const u16* __restrict__ h2b, float* __restrict__ vout) {
  __shared__ u16 Asm[176 * 256];       // 90 KB (128 rows + 24 halo each side)
  __shared__ float pvbuf[4][128][3];   // 6 KB
  int tid = threadIdx.x;
  int l = tid & 63, w = tid >> 6;
  int wm = w >> 2, wn = w & 3;
  int l15 = l & 15, hi16 = (l >> 4) * 16, l8 = l * 8;
  int bid = blockIdx.x;
  int swz = (bid & 7) * 96 + (bid >> 3);
  int r0 = swz * 128;
  char* ab = (char*)Asm;

  // stage rows [r0-24, r0+152), swizzled; 176*32 = 5632 = 11*512
#pragma unroll
  for (int p = 0; p < 11; ++p) {
    int c = tid + p * 512;
    int lr = c >> 5, c16 = c & 31;
    int grow = r0 - 24 + lr;
    grow = grow < 0 ? 0 : (grow >= M_ ? M_ - 1 : grow);
    short8v v = *(const short8v*)&h2b[(size_t)grow * 256 + c16 * 8];
    int off = (lr * 512 + c16 * 16) ^ ((lr & 7) << 4);
    *(short8v*)(ab + off) = v;
  }
  __syncthreads();

  int t0[4];
#pragma unroll
  for (int mi = 0; mi < 4; ++mi) {
    int row = r0 + wm * 64 + mi * 16 + l15;
    t0[mi] = (row / 24) & 127;
  }
  short8v z8 = {0, 0, 0, 0, 0, 0, 0, 0};

  float4v z4 = {0.f, 0.f, 0.f, 0.f};
  float4v acc[4][4];
#pragma unroll
  for (int mi = 0; mi < 4; ++mi)
#pragma unroll
    for (int ni = 0; ni < 4; ++ni) acc[mi][ni] = z4;

  const u16* wbase = wtf + (size_t)wn * 4 * 512 + l8;

#define LB_C(dst, kb) do {                                                \
  const u16* bp_ = wbase + (size_t)(kb) * 16 * 512;                       \
  _Pragma("unroll") for (int ni_ = 0; ni_ < 4; ++ni_)                     \
    dst[ni_] = *(const short8v*)(bp_ + ni_ * 512);                        \
} while (0)
#define LA_C(dst, kb) do {                                                \
  int tap_ = (kb) >> 3;                                                   \
  _Pragma("unroll") for (int mi_ = 0; mi_ < 4; ++mi_) {                   \
    int lr_ = tap_ * 24 + wm * 64 + mi_ * 16 + l15;                       \
    int off_ = (lr_ * 512 + ((kb) & 7) * 64 + hi16) ^ ((lr_ & 7) << 4);   \
    short8v v_ = *(const short8v*)(ab + off_);                            \
    if (tap_ != 1) {                                                      \
      bool ok_ = (unsigned)(t0[mi_] + tap_ - 1) < 128u;                   \
      v_ = ok_ ? v_ : z8;                                                 \
    }                                                                     \
    dst[mi_] = v_;                                                        \
  }                                                                       \
} while (0)

  // depth-4 B + depth-2 A prefetch; launch_bounds(512,2) gives 256-VGPR budget
  short8v A2[2][4], Bq[4][4];
  LB_C(Bq[0], 0); LB_C(Bq[1], 1); LB_C(Bq[2], 2); LB_C(Bq[3], 3);
  LA_C(A2[0], 0); LA_C(A2[1], 1);
#pragma unroll
  for (int kb = 0; kb < 24; ++kb) {
    DO_MFMA(A2[kb & 1], Bq[kb & 3]);
    if (kb + 4 < 24) LB_C(Bq[kb & 3], kb + 4);
    if (kb + 2 < 24) LA_C(A2[kb & 1], kb + 2);
  }
#undef LB_C
#undef LA_C

  float pv[4][4][3] = {};
#pragma unroll
  for (int ni = 0; ni < 4; ++ni) {
    int col = wn * 64 + ni * 16 + l15;
    float bc = b_conv[col], scv = bnsc[col], shv = bnsh[col];
    float w0v = w_out[col * 3], w1v = w_out[col * 3 + 1], w2v = w_out[col * 3 + 2];
#pragma unroll
    for (int mi = 0; mi < 4; ++mi)
#pragma unroll
      for (int r = 0; r < 4; ++r) {
        float hv = acc[mi][ni][r] + bc;
        hv = hv * scv + shv;
        hv = (hv >= 0.f) ? hv : SLOPE_ * hv;
        pv[mi][r][0] += hv * w0v;
        pv[mi][r][1] += hv * w1v;
        pv[mi][r][2] += hv * w2v;
      }
  }
#pragma unroll
  for (int mi = 0; mi < 4; ++mi)
#pragma unroll
    for (int r = 0; r < 4; ++r)
#pragma unroll
      for (int c = 0; c < 3; ++c) {
        float v = pv[mi][r][c];
        v += __shfl_xor(v, 1);
        v += __shfl_xor(v, 2);
        v += __shfl_xor(v, 4);
        v += __shfl_xor(v, 8);
        pv[mi][r][c] = v;
      }
  int g = l >> 4;
  if (l15 == 0) {
#pragma unroll
    for (int mi = 0; mi < 4; ++mi)
#pragma unroll
      for (int r = 0; r < 4; ++r) {
        int rl = wm * 64 + mi * 16 + g * 4 + r;
        pvbuf[wn][rl][0] = pv[mi][r][0];
        pvbuf[wn][rl][1] = pv[mi][r][1];
        pvbuf[wn][rl][2] = pv[mi][r][2];
      }
  }
  __syncthreads();
  if (tid < 384) {
    int row = tid / 3, c = tid - row * 3;
    float sum = pvbuf[0][row][c] + pvbuf[1][row][c] + pvbuf[2][row][c] +
                pvbuf[3][row][c] + b_out[c];
    vout[(size_t)(r0 + row) * 3 + c] = sum;
  }
}

extern "C" void kernel_launch(void* const* d_in, const int* in_sizes, int n_in,
                              void* d_out, int out_size, void* d_ws, size_t ws_size,
                              hipStream_t stream) {
  (void)in_sizes; (void)n_in; (void)out_size; (void)ws_size;
  const float* xt      = (const float*)d_in[0];
  const float* tau     = (const float*)d_in[1];
  const float* z       = (const float*)d_in[2];
  const float* hn      = (const float*)d_in[3];
  const float* adj     = (const float*)d_in[4];
  const float* w_joint = (const float*)d_in[5];
  const float* b_joint = (const float*)d_in[6];
  const float* w_t1    = (const float*)d_in[7];
  const float* b_t1    = (const float*)d_in[8];
  const float* w_t2    = (const float*)d_in[9];
  const float* b_t2    = (const float*)d_in[10];
  const float* w_radar = (const float*)d_in[11];
  const float* b_radar = (const float*)d_in[12];
  const float* w_gcn   = (const float*)d_in[13];
  const float* b_gcn   = (const float*)d_in[14];
  const float* w_conv  = (const float*)d_in[15];
  const float* b_conv  = (const float*)d_in[16];
  const float* gamma   = (const float*)d_in[17];
  const float* beta    = (const float*)d_in[18];
  const float* mean    = (const float*)d_in[19];
  const float* var     = (const float*)d_in[20];
  const float* w_out   = (const float*)d_in[21];
  const float* b_out   = (const float*)d_in[22];

  char* wsb = (char*)d_ws;
  u16*   hgb   = (u16*)(wsb + OB_HGB);
  u16*   hbres = (u16*)(wsb + OB_HB);
  u16*   wtf   = (u16*)(wsb + OB_WTF);
  u16*   wgf   = (u16*)(wsb + OB_WGF);
  float* basep = (float*)(wsb + OB_BASE);
  float* bnsc  = (float*)(wsb + OB_BNSC);
  float* bnsh  = (float*)(wsb + OB_BNSH);
  float* vout  = (float*)d_out;

  hipLaunchKernelGGL(k_pack2, dim3(25), dim3(256), 0, stream,
                     w_conv, w_gcn, gamma, beta, mean, var, wtf, wgf, bnsc, bnsh);
  hipLaunchKernelGGL(k_base2, dim3(256), dim3(256), 0, stream,
                     tau, w_t1, b_t1, z, hn, w_t2, w_radar, b_t2, b_radar, basep);
  hipLaunchKernelGGL(k_hg2, dim3(BT_), dim3(256), 0, stream,
                     xt, basep, adj, w_joint, b_joint, hgb, hbres);
  hipLaunchKernelGGL(k_gcn4, dim3(M_ / 128), dim3(512), 0, stream,
                     wgf, b_gcn, hbres, hgb);
  hipLaunchKernelGGL(k_conv4, dim3(M_ / 128), dim3(512), 0, stream,
                     wtf, b_conv, bnsc, bnsh, w_out, b_out, hgb, vout);
}

// Round 9
// 266.531 us; speedup vs baseline: 1.0291x; 1.0291x over previous
//
#include <hip/hip_runtime.h>

typedef __attribute__((ext_vector_type(8))) short short8v;
typedef __attribute__((ext_vector_type(4))) float float4v;
typedef unsigned short u16;

constexpr int B_ = 32, T_ = 128, J_ = 24, H_ = 256;
constexpr int BT_ = B_ * T_;   // 4096
constexpr int M_  = BT_ * J_;  // 98304
constexpr float BN_EPS_ = 1e-5f, SLOPE_ = 0.2f;

// ---- workspace byte offsets ----
constexpr size_t OB_HGB  = 0;                              // bf16 [M][256] hg
constexpr size_t OB_WTF  = OB_HGB + (size_t)M_ * H_ * 2;   // bf16 768*256 frag-packed conv W
constexpr size_t OB_WGF  = OB_WTF + 768 * 256 * 2;         // bf16 256*256 frag-packed gcn W
constexpr size_t OB_BASE = OB_WGF + 256 * 256 * 2;         // f32 [BT][256]
constexpr size_t OB_BNSC = OB_BASE + (size_t)BT_ * H_ * 4; // f32 256
constexpr size_t OB_BNSH = OB_BNSC + 256 * 4;              // f32 256

__device__ __forceinline__ u16 f2b(float f) {
  union { float f; unsigned u; } v; v.f = f;
  return (u16)((v.u + 0x7fffu + ((v.u >> 16) & 1u)) >> 16);
}

// ================================================================ k_pack2 (unchanged)
__global__ __launch_bounds__(256) void k_pack2(
    const float* __restrict__ w_conv, const float* __restrict__ w_gcn,
    const float* __restrict__ gamma, const float* __restrict__ beta,
    const float* __restrict__ mean, const float* __restrict__ var,
    u16* __restrict__ wtf, u16* __restrict__ wgf,
    float* __restrict__ bnsc, float* __restrict__ bnsh) {
  __shared__ float wlds[12288];
  int bid = blockIdx.x, tid = threadIdx.x;
  if (bid < 16) {
    int nblk = bid, o0 = nblk * 16;
#pragma unroll
    for (int p = 0; p < 12; ++p) {
      int lin = tid + p * 256;
      int row = lin / 192, c4 = lin % 192;
      *(float4*)&wlds[row * 768 + c4 * 4] =
          *(const float4*)&w_conv[(size_t)(o0 + row) * 768 + c4 * 4];
    }
    __syncthreads();
#pragma unroll
    for (int p = 0; p < 6; ++p) {
      int unit = tid + p * 256;
      int kb = unit >> 6, l = unit & 63;
      int col = l & 15, kb8 = (l >> 4) * 8;
      u16 tmp[8];
#pragma unroll
      for (int j = 0; j < 8; ++j) {
        int k = kb * 32 + kb8 + j;
        int tap = k >> 8, i = k & 255;
        tmp[j] = f2b(wlds[col * 768 + i * 3 + tap]);
      }
      *(short8v*)&wtf[((size_t)kb * 16 + nblk) * 512 + l * 8] = *(short8v*)tmp;
    }
  } else if (bid < 24) {
    int kb = bid - 16;
#pragma unroll
    for (int p = 0; p < 8; ++p) {
      int lin = tid + p * 256;
      int row = lin >> 6, c4 = lin & 63;
      *(float4*)&wlds[row * 256 + c4 * 4] =
          *(const float4*)&w_gcn[((size_t)kb * 32 + row) * 256 + c4 * 4];
    }
    __syncthreads();
#pragma unroll
    for (int p = 0; p < 4; ++p) {
      int unit = tid + p * 256;
      int nblk = unit >> 6, l = unit & 63;
      int col = l & 15, kb8 = (l >> 4) * 8;
      u16 tmp[8];
#pragma unroll
      for (int j = 0; j < 8; ++j)
        tmp[j] = f2b(wlds[(kb8 + j) * 256 + nblk * 16 + col]);
      *(short8v*)&wgf[((size_t)kb * 16 + nblk) * 512 + l * 8] = *(short8v*)tmp;
    }
  } else {
    float sc = gamma[tid] * rsqrtf(var[tid] + BN_EPS_);
    bnsc[tid] = sc;
    bnsh[tid] = beta[tid] - mean[tid] * sc;
  }
}

// ================================================================ k_base2 (unchanged)
__global__ __launch_bounds__(256) void k_base2(
    const float* __restrict__ tau, const float* __restrict__ w_t1,
    const float* __restrict__ b_t1, const float* __restrict__ z,
    const float* __restrict__ hn, const float* __restrict__ w_t2,
    const float* __restrict__ w_radar, const float* __restrict__ b_t2,
    const float* __restrict__ b_radar, float* __restrict__ basep) {
  __shared__ float As[16][40];
  __shared__ float Bs[16][128];
  int bm = blockIdx.x & 127, bn = blockIdx.x >> 7;
  int row0 = bm * 32, col0 = bn * 128;
  int tid = threadIdx.x, ty = tid >> 5, tx = tid & 31;
  int sr = tid >> 2, sq = tid & 3;
  float tauv = (tid < 128) ? tau[row0 + sr] : 0.f;
  int bb = bm >> 2;
  float acc[4][4] = {};
  for (int ck = 0; ck < 32; ++ck) {
    int half = ck >> 4;
    int k0 = (ck & 15) * 16;
    if (tid < 128) {
      int kk4 = k0 + sq * 4;
      float4 v;
      if (half == 0) {
        float4 w1  = *(const float4*)&w_t1[kk4];
        float4 bb1 = *(const float4*)&b_t1[kk4];
        float t0 = tauv * w1.x + bb1.x, t1 = tauv * w1.y + bb1.y;
        float t2 = tauv * w1.z + bb1.z, t3 = tauv * w1.w + bb1.w;
        v.x = t0 / (1.f + expf(-t0)); v.y = t1 / (1.f + expf(-t1));
        v.z = t2 / (1.f + expf(-t2)); v.w = t3 / (1.f + expf(-t3));
      } else {
        float4 zv = *(const float4*)&z[(size_t)(row0 + sr) * 256 + kk4];
        float4 hv = *(const float4*)&hn[(size_t)bb * 256 + kk4];
        v = make_float4(zv.x + hv.x, zv.y + hv.y, zv.z + hv.z, zv.w + hv.w);
      }
      As[sq * 4 + 0][sr] = v.x; As[sq * 4 + 1][sr] = v.y;
      As[sq * 4 + 2][sr] = v.z; As[sq * 4 + 3][sr] = v.w;
    }
    const float* W = half ? w_radar : w_t2;
#pragma unroll
    for (int p = 0; p < 2; ++p) {
      int idx = tid + p * 256;
      int br = idx >> 5, c4 = idx & 31;
      *(float4*)&Bs[br][c4 * 4] = *(const float4*)&W[(size_t)(k0 + br) * 256 + col0 + c4 * 4];
    }
    __syncthreads();
#pragma unroll
    for (int kk = 0; kk < 16; ++kk) {
      float4 av = *(const float4*)&As[kk][ty * 4];
      float4 bv = *(const float4*)&Bs[kk][tx * 4];
      float a[4] = {av.x, av.y, av.z, av.w};
      float b[4] = {bv.x, bv.y, bv.z, bv.w};
#pragma unroll
      for (int i = 0; i < 4; ++i)
#pragma unroll
        for (int j = 0; j < 4; ++j) acc[i][j] += a[i] * b[j];
    }
    __syncthreads();
  }
#pragma unroll
  for (int i = 0; i < 4; ++i) {
    int bt = row0 + ty * 4 + i;
    int c = col0 + tx * 4;
    float4 o;
    o.x = acc[i][0] + b_t2[c + 0] + b_radar[c + 0];
    o.y = acc[i][1] + b_t2[c + 1] + b_radar[c + 1];
    o.z = acc[i][2] + b_t2[c + 2] + b_radar[c + 2];
    o.w = acc[i][3] + b_t2[c + 3] + b_radar[c + 3];
    *(float4*)&basep[(size_t)bt * 256 + c] = o;
  }
}

// ================================================================ k_hg3 (hb dropped: mega recomputes h)
__global__ __launch_bounds__(256) void k_hg3(
    const float* __restrict__ xt, const float* __restrict__ basep,
    const float* __restrict__ adj, const float* __restrict__ w_joint,
    const float* __restrict__ b_joint, u16* __restrict__ hgb) {
  __shared__ float xs[72];
  __shared__ __align__(16) u16 stage[24][256];  // 12 KB
  int bt = blockIdx.x, c = threadIdx.x;
  if (c < 18) ((float4*)xs)[c] = ((const float4*)(xt + (size_t)bt * 72))[c];
  __syncthreads();
  float wj0 = w_joint[c], wj1 = w_joint[256 + c], wj2 = w_joint[512 + c];
  float hbase = b_joint[c] + basep[(size_t)bt * 256 + c];
  float hv[24];
#pragma unroll
  for (int j = 0; j < 24; ++j)
    hv[j] = xs[3 * j] * wj0 + xs[3 * j + 1] * wj1 + xs[3 * j + 2] * wj2 + hbase;
  float ag[24] = {};
#pragma unroll
  for (int kp = 0; kp < 24; ++kp) {
    float av = hv[kp];
#pragma unroll
    for (int j = 0; j < 24; ++j) ag[j] += adj[j * 24 + kp] * av;
  }
#pragma unroll
  for (int j = 0; j < 24; ++j) stage[j][c] = f2b(ag[j]);
  __syncthreads();
  size_t gro = (size_t)bt * 24 * 256;
#pragma unroll
  for (int p = 0; p < 3; ++p) {
    int uu = c + p * 256;
    int j = uu >> 5, c8 = uu & 31;
    *(short8v*)&hgb[gro + j * 256 + c8 * 8] = *(const short8v*)&stage[j][c8 * 8];
  }
}

// ================================================================ k_mega: GCN(192-row halo) + conv + BN + leaky + out-proj
__global__ __launch_bounds__(512, 1) void k_mega(
    const u16* __restrict__ wgf, const u16* __restrict__ wtf,
    const float* __restrict__ b_gcn, const float* __restrict__ xt,
    const float* __restrict__ basep, const float* __restrict__ w_joint,
    const float* __restrict__ b_joint, const float* __restrict__ b_conv,
    const float* __restrict__ bnsc, const float* __restrict__ bnsh,
    const float* __restrict__ w_out, const float* __restrict__ b_out,
    const u16* __restrict__ hgb, float* __restrict__ vout) {
  __shared__ u16 Asm[192 * 256];       // 96 KB: hg (staged) -> h2 (in place)
  __shared__ float pvbuf[4][128][3];   // 6 KB
  int tid = threadIdx.x;
  int l = tid & 63, w = tid >> 6;      // 8 waves
  int wm = w >> 2, wn = w & 3;         // 2m x 4n
  int l15 = l & 15, hi16 = (l >> 4) * 16, l8 = l * 8;
  int g = l >> 4;
  int bid = blockIdx.x;
  int swz = (bid & 7) * 96 + (bid >> 3);  // 768 = 8*96 bijective
  int r0 = swz * 128;
  char* ab = (char*)Asm;

  // ---- stage hg rows [r0-24, r0+168), clamped, swizzled. 192*32 = 6144 = 12*512
#pragma unroll
  for (int p = 0; p < 12; ++p) {
    int c = tid + p * 512;
    int lr = c >> 5, c16 = c & 31;
    int grow = r0 - 24 + lr;
    grow = grow < 0 ? 0 : (grow >= M_ ? M_ - 1 : grow);
    short8v v = *(const short8v*)&hgb[(size_t)grow * 256 + c16 * 8];
    int off = (lr * 512 + c16 * 16) ^ ((lr & 7) << 4);
    *(short8v*)(ab + off) = v;
  }
  __syncthreads();

  // ================= GCN GEMM over 192 staged rows (wm: 96 rows = 6 m-tiles)
  float4v z4 = {0.f, 0.f, 0.f, 0.f};
  float4v accg[6][4];
#pragma unroll
  for (int mi = 0; mi < 6; ++mi)
#pragma unroll
    for (int ni = 0; ni < 4; ++ni) accg[mi][ni] = z4;

  const u16* wb_g = wgf + (size_t)wn * 4 * 512 + l8;

#define LBG(dst, kb) do {                                                 \
  const u16* bp_ = wb_g + (size_t)(kb) * 16 * 512;                        \
  _Pragma("unroll") for (int ni_ = 0; ni_ < 4; ++ni_)                     \
    dst[ni_] = *(const short8v*)(bp_ + ni_ * 512);                        \
} while (0)
#define LAG(dst, kb) do {                                                 \
  _Pragma("unroll") for (int mi_ = 0; mi_ < 6; ++mi_) {                   \
    int lr_ = wm * 96 + mi_ * 16 + l15;                                   \
    int off_ = (lr_ * 512 + (kb) * 64 + hi16) ^ ((lr_ & 7) << 4);         \
    dst[mi_] = *(const short8v*)(ab + off_);                              \
  }                                                                       \
} while (0)
#define MFMA6(A_, B_) do {                                                \
  _Pragma("unroll") for (int mi_ = 0; mi_ < 6; ++mi_)                     \
  _Pragma("unroll") for (int ni_ = 0; ni_ < 4; ++ni_)                     \
    accg[mi_][ni_] = __builtin_amdgcn_mfma_f32_16x16x32_bf16(             \
        A_[mi_], B_[ni_], accg[mi_][ni_], 0, 0, 0);                       \
} while (0)

  {
    short8v ag0[6], ag1[6], bg0[4], bg1[4];
    LBG(bg0, 0); LBG(bg1, 1); LAG(ag0, 0); LAG(ag1, 1);
#pragma unroll
    for (int kb2 = 0; kb2 < 8; kb2 += 2) {
      MFMA6(ag0, bg0);
      if (kb2 + 2 < 8) { LBG(bg0, kb2 + 2); LAG(ag0, kb2 + 2); }
      MFMA6(ag1, bg1);
      if (kb2 + 3 < 8) { LBG(bg1, kb2 + 3); LAG(ag1, kb2 + 3); }
    }
  }
#undef LBG
#undef LAG
#undef MFMA6

  __syncthreads();  // all hg LDS reads complete before h2 overwrites

  // ---- conv B prefetch issued early (hides L2 latency under writeback VALU)
  const u16* wb_c = wtf + (size_t)wn * 4 * 512 + l8;
#define LBC(dst, kb) do {                                                 \
  const u16* bp_ = wb_c + (size_t)(kb) * 16 * 512;                        \
  _Pragma("unroll") for (int ni_ = 0; ni_ < 4; ++ni_)                     \
    dst[ni_] = *(const short8v*)(bp_ + ni_ * 512);                        \
} while (0)
  short8v Bq[4][4];
  LBC(Bq[0], 0); LBC(Bq[1], 1); LBC(Bq[2], 2); LBC(Bq[3], 3);

  // ---- h2 = h_recomp + relu(accg + b_gcn) written back into LDS (in place)
  {
    float wjc0[4], wjc1[4], wjc2[4], bjc[4], bgc[4];
#pragma unroll
    for (int ni = 0; ni < 4; ++ni) {
      int col = wn * 64 + ni * 16 + l15;
      wjc0[ni] = w_joint[col]; wjc1[ni] = w_joint[256 + col];
      wjc2[ni] = w_joint[512 + col];
      bjc[ni] = b_joint[col]; bgc[ni] = b_gcn[col];
    }
#pragma unroll
    for (int mi = 0; mi < 6; ++mi)
#pragma unroll
      for (int r = 0; r < 4; ++r) {
        int lrow = wm * 96 + mi * 16 + g * 4 + r;
        int grow = r0 - 24 + lrow;
        int growc = grow < 0 ? 0 : (grow >= M_ ? M_ - 1 : grow);
        int bt = growc / 24;
        float x0 = xt[(size_t)growc * 3 + 0];
        float x1 = xt[(size_t)growc * 3 + 1];
        float x2 = xt[(size_t)growc * 3 + 2];
#pragma unroll
        for (int ni = 0; ni < 4; ++ni) {
          int col = wn * 64 + ni * 16 + l15;
          float basev = basep[(size_t)bt * 256 + col];
          float h = x0 * wjc0[ni] + x1 * wjc1[ni] + x2 * wjc2[ni] + bjc[ni] + basev;
          float gv = accg[mi][ni][r] + bgc[ni];
          float h2 = h + (gv > 0.f ? gv : 0.f);
          int off = (lrow * 512 + col * 2) ^ ((lrow & 7) << 4);
          *(u16*)(ab + off) = f2b(h2);
        }
      }
  }
  __syncthreads();  // h2 visible to all waves

  // ================= conv GEMM (output 128 rows; wm: 64 rows = 4 m-tiles)
  int t0[4];
#pragma unroll
  for (int mi = 0; mi < 4; ++mi) {
    int row = r0 + wm * 64 + mi * 16 + l15;
    t0[mi] = (row / 24) & 127;
  }
  short8v z8 = {0, 0, 0, 0, 0, 0, 0, 0};
  float4v accc[4][4];
#pragma unroll
  for (int mi = 0; mi < 4; ++mi)
#pragma unroll
    for (int ni = 0; ni < 4; ++ni) accc[mi][ni] = z4;

#define LAC(dst, kb) do {                                                 \
  int tap_ = (kb) >> 3;                                                   \
  _Pragma("unroll") for (int mi_ = 0; mi_ < 4; ++mi_) {                   \
    int lr_ = tap_ * 24 + wm * 64 + mi_ * 16 + l15;                       \
    int off_ = (lr_ * 512 + ((kb) & 7) * 64 + hi16) ^ ((lr_ & 7) << 4);   \
    short8v v_ = *(const short8v*)(ab + off_);                            \
    if (tap_ != 1) {                                                      \
      bool ok_ = (unsigned)(t0[mi_] + tap_ - 1) < 128u;                   \
      v_ = ok_ ? v_ : z8;                                                 \
    }                                                                     \
    dst[mi_] = v_;                                                        \
  }                                                                       \
} while (0)
#define MFMA4(A_, B_) do {                                                \
  _Pragma("unroll") for (int mi_ = 0; mi_ < 4; ++mi_)                     \
  _Pragma("unroll") for (int ni_ = 0; ni_ < 4; ++ni_)                     \
    accc[mi_][ni_] = __builtin_amdgcn_mfma_f32_16x16x32_bf16(             \
        A_[mi_], B_[ni_], accc[mi_][ni_], 0, 0, 0);                       \
} while (0)

  {
    short8v A2[2][4];
    LAC(A2[0], 0); LAC(A2[1], 1);
#pragma unroll
    for (int kb = 0; kb < 24; ++kb) {
      MFMA4(A2[kb & 1], Bq[kb & 3]);
      if (kb + 4 < 24) LBC(Bq[kb & 3], kb + 4);
      if (kb + 2 < 24) LAC(A2[kb & 1], kb + 2);
    }
  }
#undef LAC
#undef LBC
#undef MFMA4

  // ---- epilogue: bias + BN + leaky + out-proj, cross-wave reduce
  float pv[4][4][3] = {};
#pragma unroll
  for (int ni = 0; ni < 4; ++ni) {
    int col = wn * 64 + ni * 16 + l15;
    float bc = b_conv[col], scv = bnsc[col], shv = bnsh[col];
    float w0v = w_out[col * 3], w1v = w_out[col * 3 + 1], w2v = w_out[col * 3 + 2];
#pragma unroll
    for (int mi = 0; mi < 4; ++mi)
#pragma unroll
      for (int r = 0; r < 4; ++r) {
        float hv = accc[mi][ni][r] + bc;
        hv = hv * scv + shv;
        hv = (hv >= 0.f) ? hv : SLOPE_ * hv;
        pv[mi][r][0] += hv * w0v;
        pv[mi][r][1] += hv * w1v;
        pv[mi][r][2] += hv * w2v;
      }
  }
#pragma unroll
  for (int mi = 0; mi < 4; ++mi)
#pragma unroll
    for (int r = 0; r < 4; ++r)
#pragma unroll
      for (int c = 0; c < 3; ++c) {
        float v = pv[mi][r][c];
        v += __shfl_xor(v, 1);
        v += __shfl_xor(v, 2);
        v += __shfl_xor(v, 4);
        v += __shfl_xor(v, 8);
        pv[mi][r][c] = v;
      }
  if (l15 == 0) {
#pragma unroll
    for (int mi = 0; mi < 4; ++mi)
#pragma unroll
      for (int r = 0; r < 4; ++r) {
        int rl = wm * 64 + mi * 16 + g * 4 + r;
        pvbuf[wn][rl][0] = pv[mi][r][0];
        pvbuf[wn][rl][1] = pv[mi][r][1];
        pvbuf[wn][rl][2] = pv[mi][r][2];
      }
  }
  __syncthreads();
  if (tid < 384) {
    int row = tid / 3, c = tid - row * 3;
    float sum = pvbuf[0][row][c] + pvbuf[1][row][c] + pvbuf[2][row][c] +
                pvbuf[3][row][c] + b_out[c];
    vout[(size_t)(r0 + row) * 3 + c] = sum;
  }
}

extern "C" void kernel_launch(void* const* d_in, const int* in_sizes, int n_in,
                              void* d_out, int out_size, void* d_ws, size_t ws_size,
                              hipStream_t stream) {
  (void)in_sizes; (void)n_in; (void)out_size; (void)ws_size;
  const float* xt      = (const float*)d_in[0];
  const float* tau     = (const float*)d_in[1];
  const float* z       = (const float*)d_in[2];
  const float* hn      = (const float*)d_in[3];
  const float* adj     = (const float*)d_in[4];
  const float* w_joint = (const float*)d_in[5];
  const float* b_joint = (const float*)d_in[6];
  const float* w_t1    = (const float*)d_in[7];
  const float* b_t1    = (const float*)d_in[8];
  const float* w_t2    = (const float*)d_in[9];
  const float* b_t2    = (const float*)d_in[10];
  const float* w_radar = (const float*)d_in[11];
  const float* b_radar = (const float*)d_in[12];
  const float* w_gcn   = (const float*)d_in[13];
  const float* b_gcn   = (const float*)d_in[14];
  const float* w_conv  = (const float*)d_in[15];
  const float* b_conv  = (const float*)d_in[16];
  const float* gamma   = (const float*)d_in[17];
  const float* beta    = (const float*)d_in[18];
  const float* mean    = (const float*)d_in[19];
  const float* var     = (const float*)d_in[20];
  const float* w_out   = (const float*)d_in[21];
  const float* b_out   = (const float*)d_in[22];

  char* wsb = (char*)d_ws;
  u16*   hgb   = (u16*)(wsb + OB_HGB);
  u16*   wtf   = (u16*)(wsb + OB_WTF);
  u16*   wgf   = (u16*)(wsb + OB_WGF);
  float* basep = (float*)(wsb + OB_BASE);
  float* bnsc  = (float*)(wsb + OB_BNSC);
  float* bnsh  = (float*)(wsb + OB_BNSH);
  float* vout  = (float*)d_out;

  hipLaunchKernelGGL(k_pack2, dim3(25), dim3(256), 0, stream,
                     w_conv, w_gcn, gamma, beta, mean, var, wtf, wgf, bnsc, bnsh);
  hipLaunchKernelGGL(k_base2, dim3(256), dim3(256), 0, stream,
                     tau, w_t1, b_t1, z, hn, w_t2, w_radar, b_t2, b_radar, basep);
  hipLaunchKernelGGL(k_hg3, dim3(BT_), dim3(256), 0, stream,
                     xt, basep, adj, w_joint, b_joint, hgb);
  hipLaunchKernelGGL(k_mega, dim3(M_ / 128), dim3(512), 0, stream,
                     wgf, wtf, b_gcn, xt, basep, w_joint, b_joint,
                     b_conv, bnsc, bnsh, w_out, b_out, hgb, vout);
}

// Round 11
// 253.337 us; speedup vs baseline: 1.0827x; 1.0521x over previous
//
#include <hip/hip_runtime.h>

typedef __attribute__((ext_vector_type(8))) short short8v;
typedef __attribute__((ext_vector_type(4))) float float4v;
typedef unsigned short u16;

constexpr int B_ = 32, T_ = 128, J_ = 24, H_ = 256;
constexpr int BT_ = B_ * T_;   // 4096
constexpr int M_  = BT_ * J_;  // 98304
constexpr float BN_EPS_ = 1e-5f, SLOPE_ = 0.2f;

// ---- workspace byte offsets (round-7 layout: hb restored) ----
constexpr size_t OB_HGB  = 0;                              // bf16 [M][256] hg -> h2 (in place)
constexpr size_t OB_HB   = OB_HGB + (size_t)M_ * H_ * 2;   // bf16 [M][256] residual h
constexpr size_t OB_WTF  = OB_HB  + (size_t)M_ * H_ * 2;   // bf16 768*256 frag-packed conv W
constexpr size_t OB_WGF  = OB_WTF + 768 * 256 * 2;         // bf16 256*256 frag-packed gcn W
constexpr size_t OB_BASE = OB_WGF + 256 * 256 * 2;         // f32 [BT][256]
constexpr size_t OB_BNSC = OB_BASE + (size_t)BT_ * H_ * 4; // f32 256
constexpr size_t OB_BNSH = OB_BNSC + 256 * 4;              // f32 256

__device__ __forceinline__ u16 f2b(float f) {
  union { float f; unsigned u; } v; v.f = f;
  return (u16)((v.u + 0x7fffu + ((v.u >> 16) & 1u)) >> 16);
}
__device__ __forceinline__ float b2f(u16 u) {
  union { unsigned u; float f; } v; v.u = ((unsigned)u) << 16; return v.f;
}

// ================================================================ k_pack2 (772-pad conv path)
__global__ __launch_bounds__(256) void k_pack2(
    const float* __restrict__ w_conv, const float* __restrict__ w_gcn,
    const float* __restrict__ gamma, const float* __restrict__ beta,
    const float* __restrict__ mean, const float* __restrict__ var,
    u16* __restrict__ wtf, u16* __restrict__ wgf,
    float* __restrict__ bnsc, float* __restrict__ bnsh) {
  __shared__ float wlds[12352];
  int bid = blockIdx.x, tid = threadIdx.x;
  if (bid < 16) {
    int nblk = bid, o0 = nblk * 16;
#pragma unroll
    for (int p = 0; p < 12; ++p) {
      int lin = tid + p * 256;
      int row = lin / 192, c4 = lin % 192;
      *(float4*)&wlds[row * 772 + c4 * 4] =
          *(const float4*)&w_conv[(size_t)(o0 + row) * 768 + c4 * 4];
    }
    __syncthreads();
#pragma unroll
    for (int p = 0; p < 6; ++p) {
      int unit = tid + p * 256;
      int kb = unit >> 6, l = unit & 63;
      int col = l & 15, kb8 = (l >> 4) * 8;
      u16 tmp[8];
#pragma unroll
      for (int j = 0; j < 8; ++j) {
        int k = kb * 32 + kb8 + j;
        int tap = k >> 8, i = k & 255;
        tmp[j] = f2b(wlds[col * 772 + i * 3 + tap]);
      }
      *(short8v*)&wtf[((size_t)kb * 16 + nblk) * 512 + l * 8] = *(short8v*)tmp;
    }
  } else if (bid < 24) {
    int kb = bid - 16;
#pragma unroll
    for (int p = 0; p < 8; ++p) {
      int lin = tid + p * 256;
      int row = lin >> 6, c4 = lin & 63;
      *(float4*)&wlds[row * 256 + c4 * 4] =
          *(const float4*)&w_gcn[((size_t)kb * 32 + row) * 256 + c4 * 4];
    }
    __syncthreads();
#pragma unroll
    for (int p = 0; p < 4; ++p) {
      int unit = tid + p * 256;
      int nblk = unit >> 6, l = unit & 63;
      int col = l & 15, kb8 = (l >> 4) * 8;
      u16 tmp[8];
#pragma unroll
      for (int j = 0; j < 8; ++j)
        tmp[j] = f2b(wlds[(kb8 + j) * 256 + nblk * 16 + col]);
      *(short8v*)&wgf[((size_t)kb * 16 + nblk) * 512 + l * 8] = *(short8v*)tmp;
    }
  } else {
    float sc = gamma[tid] * rsqrtf(var[tid] + BN_EPS_);
    bnsc[tid] = sc;
    bnsh[tid] = beta[tid] - mean[tid] * sc;
  }
}

// ================================================================ k_base3v2: register-prefetch, single-buffer, 2 barriers
// base = silu(tau w1+b1)@w_t2 + (z+hn)@w_radar + b_t2 + b_radar
__global__ __launch_bounds__(256) void k_base3(
    const float* __restrict__ tau, const float* __restrict__ w_t1,
    const float* __restrict__ b_t1, const float* __restrict__ z,
    const float* __restrict__ hn, const float* __restrict__ w_t2,
    const float* __restrict__ w_radar, const float* __restrict__ b_t2,
    const float* __restrict__ b_radar, float* __restrict__ basep) {
  __shared__ float As[16][40];
  __shared__ float Bs[16][128];
  int bm = blockIdx.x & 127, bn = blockIdx.x >> 7;
  int row0 = bm * 32, col0 = bn * 128;
  int tid = threadIdx.x, ty = tid >> 5, tx = tid & 31;
  int sr = tid >> 2, sq = tid & 3;
  float tauv = (tid < 128) ? tau[row0 + sr] : 0.f;
  int bb = bm >> 2;

  float4 rA = make_float4(0.f, 0.f, 0.f, 0.f);
  float4 rB0, rB1;
#define LD_STEP(ck) do {                                                   \
    int half_ = (ck) >> 4;                                                 \
    int k0_ = ((ck) & 15) * 16;                                            \
    if (tid < 128) {                                                       \
      int kk4_ = k0_ + sq * 4;                                             \
      if (half_ == 0) {                                                    \
        float4 w1_  = *(const float4*)&w_t1[kk4_];                         \
        float4 bb1_ = *(const float4*)&b_t1[kk4_];                         \
        float t0_ = tauv * w1_.x + bb1_.x, t1_ = tauv * w1_.y + bb1_.y;    \
        float t2_ = tauv * w1_.z + bb1_.z, t3_ = tauv * w1_.w + bb1_.w;    \
        rA.x = t0_ / (1.f + expf(-t0_)); rA.y = t1_ / (1.f + expf(-t1_));  \
        rA.z = t2_ / (1.f + expf(-t2_)); rA.w = t3_ / (1.f + expf(-t3_));  \
      } else {                                                             \
        float4 zv_ = *(const float4*)&z[(size_t)(row0 + sr) * 256 + k0_ + sq * 4]; \
        float4 hv_ = *(const float4*)&hn[(size_t)bb * 256 + k0_ + sq * 4]; \
        rA = make_float4(zv_.x + hv_.x, zv_.y + hv_.y, zv_.z + hv_.z, zv_.w + hv_.w); \
      }                                                                    \
    }                                                                      \
    const float* W_ = half_ ? w_radar : w_t2;                              \
    {                                                                      \
      int idx_ = tid, br_ = idx_ >> 5, c4_ = idx_ & 31;                    \
      rB0 = *(const float4*)&W_[(size_t)(k0_ + br_) * 256 + col0 + c4_ * 4]; \
      idx_ = tid + 256; br_ = idx_ >> 5; c4_ = idx_ & 31;                  \
      rB1 = *(const float4*)&W_[(size_t)(k0_ + br_) * 256 + col0 + c4_ * 4]; \
    }                                                                      \
} while (0)
#define ST_STEP() do {                                                     \
    if (tid < 128) {                                                       \
      As[sq * 4 + 0][sr] = rA.x; As[sq * 4 + 1][sr] = rA.y;                \
      As[sq * 4 + 2][sr] = rA.z; As[sq * 4 + 3][sr] = rA.w;                \
    }                                                                      \
    { int idx_ = tid, br_ = idx_ >> 5, c4_ = idx_ & 31;                    \
      *(float4*)&Bs[br_][c4_ * 4] = rB0;                                   \
      idx_ = tid + 256; br_ = idx_ >> 5; c4_ = idx_ & 31;                  \
      *(float4*)&Bs[br_][c4_ * 4] = rB1; }                                 \
} while (0)

  float acc[4][4] = {};
  LD_STEP(0);
  for (int ck = 0; ck < 32; ++ck) {
    ST_STEP();                 // regs -> LDS
    __syncthreads();           // LDS visible to all
    if (ck + 1 < 32) LD_STEP(ck + 1);  // next step's loads fly under compute
#pragma unroll
    for (int kk = 0; kk < 16; ++kk) {
      float4 av = *(const float4*)&As[kk][ty * 4];
      float4 bv = *(const float4*)&Bs[kk][tx * 4];
      float a[4] = {av.x, av.y, av.z, av.w};
      float b[4] = {bv.x, bv.y, bv.z, bv.w};
#pragma unroll
      for (int i = 0; i < 4; ++i)
#pragma unroll
        for (int j = 0; j < 4; ++j) acc[i][j] += a[i] * b[j];
    }
    __syncthreads();           // all LDS reads done before next ST
  }
#undef LD_STEP
#undef ST_STEP
#pragma unroll
  for (int i = 0; i < 4; ++i) {
    int bt = row0 + ty * 4 + i;
    int c = col0 + tx * 4;
    float4 o;
    o.x = acc[i][0] + b_t2[c + 0] + b_radar[c + 0];
    o.y = acc[i][1] + b_t2[c + 1] + b_radar[c + 1];
    o.z = acc[i][2] + b_t2[c + 2] + b_radar[c + 2];
    o.w = acc[i][3] + b_t2[c + 3] + b_radar[c + 3];
    *(float4*)&basep[(size_t)bt * 256 + c] = o;
  }
}

// ================================================================ k_hg2 (round-7 verbatim)
__global__ __launch_bounds__(256) void k_hg2(
    const float* __restrict__ xt, const float* __restrict__ basep,
    const float* __restrict__ adj, const float* __restrict__ w_joint,
    const float* __restrict__ b_joint, u16* __restrict__ hgb,
    u16* __restrict__ hb) {
  __shared__ float xs[72];
  __shared__ __align__(16) u16 stage[2][24][256];
  int bt = blockIdx.x, c = threadIdx.x;
  if (c < 18) ((float4*)xs)[c] = ((const float4*)(xt + (size_t)bt * 72))[c];
  __syncthreads();
  float wj0 = w_joint[c], wj1 = w_joint[256 + c], wj2 = w_joint[512 + c];
  float hbase = b_joint[c] + basep[(size_t)bt * 256 + c];
  float hv[24];
#pragma unroll
  for (int j = 0; j < 24; ++j) {
    hv[j] = xs[3 * j] * wj0 + xs[3 * j + 1] * wj1 + xs[3 * j + 2] * wj2 + hbase;
    stage[0][j][c] = f2b(hv[j]);
  }
  float ag[24] = {};
#pragma unroll
  for (int kp = 0; kp < 24; ++kp) {
    float av = hv[kp];
#pragma unroll
    for (int j = 0; j < 24; ++j) ag[j] += adj[j * 24 + kp] * av;
  }
#pragma unroll
  for (int j = 0; j < 24; ++j) stage[1][j][c] = f2b(ag[j]);
  __syncthreads();
  size_t gro = (size_t)bt * 24 * 256;
#pragma unroll
  for (int p = 0; p < 3; ++p) {
    int uu = c + p * 256;
    int j = uu >> 5, c8 = uu & 31;
    *(short8v*)&hb[gro + j * 256 + c8 * 8] = *(const short8v*)&stage[0][j][c8 * 8];
  }
#pragma unroll
  for (int p = 0; p < 3; ++p) {
    int uu = c + p * 256;
    int j = uu >> 5, c8 = uu & 31;
    *(short8v*)&hgb[gro + j * 256 + c8 * 8] = *(const short8v*)&stage[1][j][c8 * 8];
  }
}

// ================================================================ barrier-free MFMA GEMMs (round-7 verbatim)
#define DO_MFMA(A_, B_) do {                                              \
  _Pragma("unroll") for (int mi_ = 0; mi_ < 4; ++mi_)                     \
  _Pragma("unroll") for (int ni_ = 0; ni_ < 4; ++ni_)                     \
    acc[mi_][ni_] = __builtin_amdgcn_mfma_f32_16x16x32_bf16(              \
        A_[mi_], B_[ni_], acc[mi_][ni_], 0, 0, 0);                        \
} while (0)

__global__ __launch_bounds__(256) void k_gcn3(
    const u16* __restrict__ wgf, const float* __restrict__ b_gcn,
    const u16* __restrict__ hb, u16* __restrict__ hgb) {
  __shared__ u16 Asm[64 * 256];
  int tid = threadIdx.x;
  int l = tid & 63, wn = tid >> 6;
  int l15 = l & 15, hi16 = (l >> 4) * 16, l8 = l * 8;
  int bid = blockIdx.x;
  int swz = (bid & 7) * 192 + (bid >> 3);
  int r0 = swz * 64;
  char* ab = (char*)Asm;

#pragma unroll
  for (int p = 0; p < 8; ++p) {
    int c = tid + p * 256;
    int lr = c >> 5, c16 = c & 31;
    short8v v = *(const short8v*)&hgb[(size_t)(r0 + lr) * 256 + c16 * 8];
    int off = (lr * 512 + c16 * 16) ^ ((lr & 7) << 4);
    *(short8v*)(ab + off) = v;
  }
  __syncthreads();

  float4v z4 = {0.f, 0.f, 0.f, 0.f};
  float4v acc[4][4];
#pragma unroll
  for (int mi = 0; mi < 4; ++mi)
#pragma unroll
    for (int ni = 0; ni < 4; ++ni) acc[mi][ni] = z4;

  const u16* wbase = wgf + (size_t)wn * 4 * 512 + l8;

#define LB_G(dst, kb) do {                                                \
  const u16* bp_ = wbase + (size_t)(kb) * 16 * 512;                       \
  _Pragma("unroll") for (int ni_ = 0; ni_ < 4; ++ni_)                     \
    dst[ni_] = *(const short8v*)(bp_ + ni_ * 512);                        \
} while (0)
#define LA_G(dst, kb) do {                                                \
  _Pragma("unroll") for (int mi_ = 0; mi_ < 4; ++mi_) {                   \
    int lr_ = mi_ * 16 + l15;                                             \
    int off_ = (lr_ * 512 + (kb) * 64 + hi16) ^ ((lr_ & 7) << 4);         \
    dst[mi_] = *(const short8v*)(ab + off_);                              \
  }                                                                       \
} while (0)

  short8v a0[4], a1[4], b0[4], b1[4];
  LB_G(b0, 0); LB_G(b1, 1); LA_G(a0, 0); LA_G(a1, 1);
#pragma unroll
  for (int kb2 = 0; kb2 < 8; kb2 += 2) {
    DO_MFMA(a0, b0);
    if (kb2 + 2 < 8) { LB_G(b0, kb2 + 2); LA_G(a0, kb2 + 2); }
    DO_MFMA(a1, b1);
    if (kb2 + 3 < 8) { LB_G(b1, kb2 + 3); LA_G(a1, kb2 + 3); }
  }
#undef LB_G
#undef LA_G

  int g = l >> 4;
#pragma unroll
  for (int ni = 0; ni < 4; ++ni) {
    int col = wn * 64 + ni * 16 + l15;
    float bg = b_gcn[col];
#pragma unroll
    for (int mi = 0; mi < 4; ++mi)
#pragma unroll
      for (int r = 0; r < 4; ++r) {
        int row = r0 + mi * 16 + g * 4 + r;
        float hres = b2f(hb[(size_t)row * 256 + col]);
        float gv = acc[mi][ni][r] + bg;
        hgb[(size_t)row * 256 + col] = f2b(hres + (gv > 0.f ? gv : 0.f));
      }
  }
}

__global__ __launch_bounds__(256) void k_conv3(
    const u16* __restrict__ wtf, const float* __restrict__ b_conv,
    const float* __restrict__ bnsc, const float* __restrict__ bnsh,
    const float* __restrict__ w_out, const float* __restrict__ b_out,
    const u16* __restrict__ h2b, float* __restrict__ vout) {
  __shared__ u16 Asm[112 * 256];
  __shared__ float pvbuf[4][64][3];
  int tid = threadIdx.x;
  int l = tid & 63, wn = tid >> 6;
  int l15 = l & 15, hi16 = (l >> 4) * 16, l8 = l * 8;
  int bid = blockIdx.x;
  int swz = (bid & 7) * 192 + (bid >> 3);
  int r0 = swz * 64;
  char* ab = (char*)Asm;

#pragma unroll
  for (int p = 0; p < 14; ++p) {
    int c = tid + p * 256;
    int lr = c >> 5, c16 = c & 31;
    int grow = r0 - 24 + lr;
    grow = grow < 0 ? 0 : (grow >= M_ ? M_ - 1 : grow);
    short8v v = *(const short8v*)&h2b[(size_t)grow * 256 + c16 * 8];
    int off = (lr * 512 + c16 * 16) ^ ((lr & 7) << 4);
    *(short8v*)(ab + off) = v;
  }
  __syncthreads();

  int t0[4];
#pragma unroll
  for (int mi = 0; mi < 4; ++mi) {
    int row = r0 + mi * 16 + l15;
    t0[mi] = (row / 24) & 127;
  }
  short8v z8 = {0, 0, 0, 0, 0, 0, 0, 0};

  float4v z4 = {0.f, 0.f, 0.f, 0.f};
  float4v acc[4][4];
#pragma unroll
  for (int mi = 0; mi < 4; ++mi)
#pragma unroll
    for (int ni = 0; ni < 4; ++ni) acc[mi][ni] = z4;

  const u16* wbase = wtf + (size_t)wn * 4 * 512 + l8;

#define LB_C(dst, kb) do {                                                \
  const u16* bp_ = wbase + (size_t)(kb) * 16 * 512;                       \
  _Pragma("unroll") for (int ni_ = 0; ni_ < 4; ++ni_)                     \
    dst[ni_] = *(const short8v*)(bp_ + ni_ * 512);                        \
} while (0)
#define LA_C(dst, kb) do {                                                \
  int tap_ = (kb) >> 3;                                                   \
  _Pragma("unroll") for (int mi_ = 0; mi_ < 4; ++mi_) {                   \
    int lr_ = tap_ * 24 + mi_ * 16 + l15;                                 \
    int off_ = (lr_ * 512 + ((kb) & 7) * 64 + hi16) ^ ((lr_ & 7) << 4);   \
    short8v v_ = *(const short8v*)(ab + off_);                            \
    if (tap_ != 1) {                                                      \
      bool ok_ = (unsigned)(t0[mi_] + tap_ - 1) < 128u;                   \
      v_ = ok_ ? v_ : z8;                                                 \
    }                                                                     \
    dst[mi_] = v_;                                                        \
  }                                                                       \
} while (0)

  short8v A2[2][4], Bq[4][4];
  LB_C(Bq[0], 0); LB_C(Bq[1], 1); LB_C(Bq[2], 2); LB_C(Bq[3], 3);
  LA_C(A2[0], 0); LA_C(A2[1], 1);
#pragma unroll
  for (int kb = 0; kb < 24; ++kb) {
    DO_MFMA(A2[kb & 1], Bq[kb & 3]);
    if (kb + 4 < 24) LB_C(Bq[kb & 3], kb + 4);
    if (kb + 2 < 24) LA_C(A2[kb & 1], kb + 2);
  }
#undef LB_C
#undef LA_C

  float pv[4][4][3] = {};
#pragma unroll
  for (int ni = 0; ni < 4; ++ni) {
    int col = wn * 64 + ni * 16 + l15;
    float bc = b_conv[col], scv = bnsc[col], shv = bnsh[col];
    float w0v = w_out[col * 3], w1v = w_out[col * 3 + 1], w2v = w_out[col * 3 + 2];
#pragma unroll
    for (int mi = 0; mi < 4; ++mi)
#pragma unroll
      for (int r = 0; r < 4; ++r) {
        float hv = acc[mi][ni][r] + bc;
        hv = hv * scv + shv;
        hv = (hv >= 0.f) ? hv : SLOPE_ * hv;
        pv[mi][r][0] += hv * w0v;
        pv[mi][r][1] += hv * w1v;
        pv[mi][r][2] += hv * w2v;
      }
  }
#pragma unroll
  for (int mi = 0; mi < 4; ++mi)
#pragma unroll
    for (int r = 0; r < 4; ++r)
#pragma unroll
      for (int c = 0; c < 3; ++c) {
        float v = pv[mi][r][c];
        v += __shfl_xor(v, 1);
        v += __shfl_xor(v, 2);
        v += __shfl_xor(v, 4);
        v += __shfl_xor(v, 8);
        pv[mi][r][c] = v;
      }
  int g = l >> 4;
  if (l15 == 0) {
#pragma unroll
    for (int mi = 0; mi < 4; ++mi)
#pragma unroll
      for (int r = 0; r < 4; ++r) {
        int rl = mi * 16 + g * 4 + r;
        pvbuf[wn][rl][0] = pv[mi][r][0];
        pvbuf[wn][rl][1] = pv[mi][r][1];
        pvbuf[wn][rl][2] = pv[mi][r][2];
      }
  }
  __syncthreads();
  if (tid < 192) {
    int row = tid / 3, c = tid - row * 3;
    float sum = pvbuf[0][row][c] + pvbuf[1][row][c] + pvbuf[2][row][c] +
                pvbuf[3][row][c] + b_out[c];
    vout[(size_t)(r0 + row) * 3 + c] = sum;
  }
}

extern "C" void kernel_launch(void* const* d_in, const int* in_sizes, int n_in,
                              void* d_out, int out_size, void* d_ws, size_t ws_size,
                              hipStream_t stream) {
  (void)in_sizes; (void)n_in; (void)out_size; (void)ws_size;
  const float* xt      = (const float*)d_in[0];
  const float* tau     = (const float*)d_in[1];
  const float* z       = (const float*)d_in[2];
  const float* hn      = (const float*)d_in[3];
  const float* adj     = (const float*)d_in[4];
  const float* w_joint = (const float*)d_in[5];
  const float* b_joint = (const float*)d_in[6];
  const float* w_t1    = (const float*)d_in[7];
  const float* b_t1    = (const float*)d_in[8];
  const float* w_t2    = (const float*)d_in[9];
  const float* b_t2    = (const float*)d_in[10];
  const float* w_radar = (const float*)d_in[11];
  const float* b_radar = (const float*)d_in[12];
  const float* w_gcn   = (const float*)d_in[13];
  const float* b_gcn   = (const float*)d_in[14];
  const float* w_conv  = (const float*)d_in[15];
  const float* b_conv  = (const float*)d_in[16];
  const float* gamma   = (const float*)d_in[17];
  const float* beta    = (const float*)d_in[18];
  const float* mean    = (const float*)d_in[19];
  const float* var     = (const float*)d_in[20];
  const float* w_out   = (const float*)d_in[21];
  const float* b_out   = (const float*)d_in[22];

  char* wsb = (char*)d_ws;
  u16*   hgb   = (u16*)(wsb + OB_HGB);
  u16*   hbres = (u16*)(wsb + OB_HB);
  u16*   wtf   = (u16*)(wsb + OB_WTF);
  u16*   wgf   = (u16*)(wsb + OB_WGF);
  float* basep = (float*)(wsb + OB_BASE);
  float* bnsc  = (float*)(wsb + OB_BNSC);
  float* bnsh  = (float*)(wsb + OB_BNSH);
  float* vout  = (float*)d_out;

  hipLaunchKernelGGL(k_pack2, dim3(25), dim3(256), 0, stream,
                     w_conv, w_gcn, gamma, beta, mean, var, wtf, wgf, bnsc, bnsh);
  hipLaunchKernelGGL(k_base3, dim3(256), dim3(256), 0, stream,
                     tau, w_t1, b_t1, z, hn, w_t2, w_radar, b_t2, b_radar, basep);
  hipLaunchKernelGGL(k_hg2, dim3(BT_), dim3(256), 0, stream,
                     xt, basep, adj, w_joint, b_joint, hgb, hbres);
  hipLaunchKernelGGL(k_gcn3, dim3(M_ / 64), dim3(256), 0, stream,
                     wgf, b_gcn, hbres, hgb);
  hipLaunchKernelGGL(k_conv3, dim3(M_ / 64), dim3(256), 0, stream,
                     wtf, b_conv, bnsc, bnsh, w_out, b_out, hgb, vout);
}